// Round 1
// baseline (1030.713 us; speedup 1.0000x reference)
//
#include <hip/hip_runtime.h>
#include <hip/hip_bf16.h>
#include <cmath>

#define NROWS 100000
#define DIM   1024
#define LH    128
#define NSEG  16
#define EPSF  1e-16f

#define OUT_OFF   0
#define SCORE_OFF (NSEG * DIM)            /* 16384   */
#define SM_OFF    (SCORE_OFF + NROWS)     /* 116384  */
#define FEAT_OFF  (SM_OFF + NROWS)        /* 216384  */

typedef __attribute__((ext_vector_type(4))) float floatx4;
typedef __attribute__((ext_vector_type(8))) short shortx8;

__device__ __forceinline__ unsigned short f2bf(float x) {
    unsigned u = __float_as_uint(x);
    u += 0x7FFFu + ((u >> 16) & 1u);          // round-to-nearest-even
    return (unsigned short)(u >> 16);
}
__device__ __forceinline__ unsigned enc_f32(float f) {   // monotone float->uint
    unsigned u = __float_as_uint(f);
    return (u & 0x80000000u) ? ~u : (u | 0x80000000u);
}
__device__ __forceinline__ float dec_f32(unsigned e) {
    unsigned u = (e & 0x80000000u) ? (e ^ 0x80000000u) : ~e;
    return __uint_as_float(u);
}

// ---------------------------------------------------------------- init -----
// Convert Wa,Wb (fp32) -> combined bf16 W[256][1024] in ws; zero segmax,
// denom, and the out-accumulator section of d_out. Runs every launch (ws and
// d_out are re-poisoned by the harness before each timed call).
__global__ void init_kernel(const float* __restrict__ Wa,
                            const float* __restrict__ Wb,
                            unsigned short* __restrict__ wbf,
                            unsigned* __restrict__ segmax,
                            float* __restrict__ denom,
                            float* __restrict__ out) {
    int idx = blockIdx.x * 256 + threadIdx.x;      // grid covers 262144
    if (idx < LH * DIM)
        wbf[idx] = f2bf(Wa[idx]);
    else if (idx < 2 * LH * DIM)
        wbf[idx] = f2bf(Wb[idx - LH * DIM]);
    if (idx < NSEG * DIM) out[OUT_OFF + idx] = 0.f;
    if (idx < NSEG) { segmax[idx] = 0u; denom[idx] = 0.f; }
}

// --------------------------------------------------------------- score -----
// Block = 256 thr (4 waves). Tile: 64 rows x 256 cols, K=1024 in chunks of 64.
// Wave w computes rows 16w..16w+15 against all 256 weight rows (16 col-tiles).
// Also echoes feature -> d_out and does block-level segment max.
__launch_bounds__(256)
__global__ void score_kernel(const float* __restrict__ feature,
                             const int* __restrict__ batch,
                             const unsigned short* __restrict__ wbf,
                             const float* __restrict__ ba,
                             const float* __restrict__ bb,
                             const float* __restrict__ wc,
                             const float* __restrict__ bc,
                             float* __restrict__ outp,
                             unsigned* __restrict__ segmax) {
    // +8 bf16 pad -> row stride 144 B -> worst 2-way LDS bank aliasing (free)
    __shared__ __align__(16) unsigned short sA[64][72];
    __shared__ __align__(16) unsigned short sW[256][72];
    __shared__ float sBias[3 * LH];
    __shared__ float sScore[64];
    __shared__ int   sBatch[64];
    __shared__ unsigned sMax[NSEG];

    const int tid  = threadIdx.x;
    const int wave = tid >> 6;
    const int lane = tid & 63;
    const int q    = lane >> 4;    // quad (k-group / row-group)
    const int c    = lane & 15;    // col within 16-tile / row within A-tile
    const int row0 = blockIdx.x * 64;

    if (tid < LH) {
        sBias[tid]          = ba[tid];
        sBias[LH + tid]     = bb[tid];
        sBias[2 * LH + tid] = wc[tid];
    }
    if (tid < NSEG) sMax[tid] = 0u;

    floatx4 acc[16];
#pragma unroll
    for (int t = 0; t < 16; ++t)
#pragma unroll
        for (int i = 0; i < 4; ++i) acc[t][i] = 0.f;

    for (int k0 = 0; k0 < DIM; k0 += 64) {
        __syncthreads();
        // ---- stage A tile (fp32 -> bf16) + feature echo ----
        {
            const int rr = tid >> 4;          // 0..15
            const int cc = (tid & 15) << 2;   // 0..60 step 4
#pragma unroll
            for (int p = 0; p < 4; ++p) {
                const int r    = p * 16 + rr;
                const int grow = row0 + r;
                floatx4 v; v[0] = v[1] = v[2] = v[3] = 0.f;
                if (grow < NROWS) {
                    v = *(const floatx4*)(feature + (size_t)grow * DIM + k0 + cc);
                    *(floatx4*)(outp + FEAT_OFF + (size_t)grow * DIM + k0 + cc) = v;
                }
                sA[r][cc + 0] = f2bf(v[0]);
                sA[r][cc + 1] = f2bf(v[1]);
                sA[r][cc + 2] = f2bf(v[2]);
                sA[r][cc + 3] = f2bf(v[3]);
            }
        }
        // ---- stage W tile (already bf16 in ws) ----
        {
#pragma unroll
            for (int p = 0; p < 8; ++p) {
                const int chunk = p * 256 + tid;    // 0..2047
                const int r  = chunk >> 3;          // 0..255
                const int cc = (chunk & 7) << 3;    // 0..56 step 8
                shortx8 v = *(const shortx8*)(wbf + (size_t)r * DIM + k0 + cc);
                *(shortx8*)&sW[r][cc] = v;
            }
        }
        __syncthreads();
        // ---- MFMA: 2 k-steps of 32, 16 col-tiles ----
#pragma unroll
        for (int ks = 0; ks < 2; ++ks) {
            const int kk = ks * 32 + q * 8;
            shortx8 a = *(const shortx8*)&sA[wave * 16 + c][kk];
#pragma unroll
            for (int t = 0; t < 16; ++t) {
                shortx8 b = *(const shortx8*)&sW[t * 16 + c][kk];
                acc[t] = __builtin_amdgcn_mfma_f32_16x16x32_bf16(a, b, acc[t], 0, 0, 0);
            }
        }
    }

    // ---- epilogue: bias + sigmoid*tanh gate + Wc dot ----
    float p4[4] = {0.f, 0.f, 0.f, 0.f};
#pragma unroll
    for (int t = 0; t < 8; ++t) {
        const int col = t * 16 + c;
        const float bav = sBias[col];
        const float bbv = sBias[LH + col];
        const float wcv = sBias[2 * LH + col];
#pragma unroll
        for (int i = 0; i < 4; ++i) {
            float u = acc[t][i] + bav;         // a-logit
            float v = acc[t + 8][i] + bbv;     // b-logit
            float sg = 1.f / (1.f + __expf(-u));
            float th = tanhf(v);
            p4[i] += sg * th * wcv;
        }
    }
#pragma unroll
    for (int i = 0; i < 4; ++i) {              // reduce over 16 cols (width-16 groups)
        p4[i] += __shfl_xor(p4[i], 1, 16);
        p4[i] += __shfl_xor(p4[i], 2, 16);
        p4[i] += __shfl_xor(p4[i], 4, 16);
        p4[i] += __shfl_xor(p4[i], 8, 16);
    }

    __syncthreads();
    if (tid < 64) sBatch[tid] = -1;
    __syncthreads();

    const float bcv = bc[0];
    if (c == 0) {
#pragma unroll
        for (int i = 0; i < 4; ++i) {
            const int r    = wave * 16 + q * 4 + i;
            const int grow = row0 + r;
            if (grow < NROWS) {
                const float s = p4[i] + bcv;
                outp[SCORE_OFF + grow] = s;
                sScore[r] = s;
                sBatch[r] = batch[grow];
            }
        }
    }
    __syncthreads();
    if (tid < 64 && sBatch[tid] >= 0)
        atomicMax(&sMax[sBatch[tid]], enc_f32(sScore[tid]));
    __syncthreads();
    if (tid < NSEG && sMax[tid] != 0u)
        atomicMax(&segmax[tid], sMax[tid]);
}

// ----------------------------------------------------------------- exp -----
__global__ void exp_kernel(const float* __restrict__ score,
                           const int* __restrict__ batch,
                           const unsigned* __restrict__ segmax,
                           float* __restrict__ evals,
                           float* __restrict__ denom) {
    __shared__ float sden[NSEG];
    const int tid = threadIdx.x;
    const int idx = blockIdx.x * 256 + tid;
    if (tid < NSEG) sden[tid] = 0.f;
    __syncthreads();
    if (idx < NROWS) {
        const int b = batch[idx];
        const float m = dec_f32(segmax[b]);
        const float e = expf(score[idx] - m);
        evals[idx] = e;
        atomicAdd(&sden[b], e);
    }
    __syncthreads();
    if (tid < NSEG && sden[tid] != 0.f) atomicAdd(&denom[tid], sden[tid]);
}

// ---------------------------------------------------------------- wsum -----
// 128 rows per block; thread owns 4 cols. Normalizes e -> softmax in place,
// accumulates softmax*feature per segment, flushing on (sorted) seg change.
__launch_bounds__(256)
__global__ void wsum_kernel(const float* __restrict__ feature,
                            const int* __restrict__ batch,
                            const float* __restrict__ denom,
                            float* __restrict__ evals,   // in: e, out: softmax
                            float* __restrict__ outp) {
    __shared__ float sw[128];
    __shared__ int   sb[128];
    const int tid = threadIdx.x;
    const int r0  = blockIdx.x * 128;

    if (tid < 128) {
        const int row = r0 + tid;
        if (row < NROWS) {
            const int b = batch[row];
            const float w = evals[row] / (denom[b] + EPSF);
            evals[row] = w;                    // score_softmax output
            sw[tid] = w;
            sb[tid] = b;
        } else {
            sw[tid] = 0.f;
            sb[tid] = -1;
        }
    }
    __syncthreads();

    floatx4 acc; acc[0] = acc[1] = acc[2] = acc[3] = 0.f;
    int curseg = -1;
    const int cc = tid * 4;
    for (int r = 0; r < 128; ++r) {
        const int b = sb[r];
        if (b < 0) break;                      // sorted: tail only
        if (b != curseg) {
            if (curseg >= 0) {
#pragma unroll
                for (int j = 0; j < 4; ++j)
                    atomicAdd(&outp[OUT_OFF + curseg * DIM + cc + j], acc[j]);
            }
            curseg = b;
            acc[0] = acc[1] = acc[2] = acc[3] = 0.f;
        }
        const floatx4 f = *(const floatx4*)(feature + (size_t)(r0 + r) * DIM + cc);
        const float w = sw[r];
        acc[0] += w * f[0];
        acc[1] += w * f[1];
        acc[2] += w * f[2];
        acc[3] += w * f[3];
    }
    if (curseg >= 0) {
#pragma unroll
        for (int j = 0; j < 4; ++j)
            atomicAdd(&outp[OUT_OFF + curseg * DIM + cc + j], acc[j]);
    }
}

// -------------------------------------------------------------- launch -----
extern "C" void kernel_launch(void* const* d_in, const int* in_sizes, int n_in,
                              void* d_out, int out_size, void* d_ws, size_t ws_size,
                              hipStream_t stream) {
    const float* feature = (const float*)d_in[0];
    const int*   batch   = (const int*)d_in[1];
    const float* Wa      = (const float*)d_in[2];
    const float* ba      = (const float*)d_in[3];
    const float* Wb      = (const float*)d_in[4];
    const float* bb      = (const float*)d_in[5];
    const float* Wc      = (const float*)d_in[6];
    const float* bc      = (const float*)d_in[7];
    float* out = (float*)d_out;

    unsigned short* wbf = (unsigned short*)d_ws;                       // 512 KB
    unsigned* segmax = (unsigned*)((char*)d_ws + 2 * LH * DIM * 2);    // 16 u32
    float*    denom  = (float*)((char*)d_ws + 2 * LH * DIM * 2 + 64);  // 16 f32

    init_kernel<<<(2 * LH * DIM) / 256, 256, 0, stream>>>(Wa, Wb, wbf, segmax, denom, out);
    score_kernel<<<(NROWS + 63) / 64, 256, 0, stream>>>(feature, batch, wbf, ba, bb, Wc, bc, out, segmax);
    exp_kernel<<<(NROWS + 255) / 256, 256, 0, stream>>>(out + SCORE_OFF, batch, segmax, out + SM_OFF, denom);
    wsum_kernel<<<(NROWS + 127) / 128, 256, 0, stream>>>(feature, batch, denom, out + SM_OFF, out);
}